// Round 12
// baseline (907.217 us; speedup 1.0000x reference)
//
#include <hip/hip_runtime.h>
#include <math.h>

// LSTMEncoder N=2048, T=128, H=256. 4-way column-split, W register-resident.
// 256 blocks x 1024 thr (16 waves). Block (q4=bid>>6, g=bid&63): rows g*32..+31,
// h-cols q4*64..+63. Wave w owns one 16-wide n-tile: n=c*4+q (c=h-col, q=gate).
// W slice = 9 frags (8 K-tiles W_hh + folded x/bias tile) = 36 VGPR, loaded once.
// Exchange via Infinity Cache, TAGGED 16B units {3 dwords=6 bf16, tag=t}:
// data dwords -> vmcnt drain (DATA ONLY) -> tag dword. R12: out-stores moved
// AFTER the tag (they were inside the drain = on the critical path), and LDS h
// double-buffered (hsh[2]) so the GEMM(reads parity p) never aliases EW(writes
// parity p^1) -> BAR2 deleted, 2 barriers/step.
// Consumers ISSUE unit loads early, overlap x-pack, ONE check, s_sleep backoff
// retries only for stale lanes. EW: quad-transpose via templated ds_swizzle.

#define TT 128
#define NH 256

typedef __attribute__((ext_vector_type(4))) float f32x4;
typedef __attribute__((ext_vector_type(8))) short s16x8;
typedef union { uint4 u4; s16x8 s; unsigned u[4]; } frag_u;

// ws layout (bytes):
//   wsW [0, 589824)        : 576 frags x 64 lanes x 16B
//   pub [589824, 3391488)  : [2 parity][256 bid][342 units x 16B]
#define OFF_PUB   589824
#define PUB_UNITS 342
#define NUNITS3   (3 * PUB_UNITS)
#define PUB_STRIDE (PUB_UNITS * 16)
#define PUB_BYTES (2 * 256 * PUB_STRIDE)

__device__ __forceinline__ unsigned short f2bf(float x) {
    unsigned u = __float_as_uint(x);
    return (unsigned short)((u + 0x7FFFu + ((u >> 16) & 1u)) >> 16);
}
__device__ __forceinline__ float bf2f(unsigned b) {
    return __uint_as_float(b << 16);
}

template<int PAT>
__device__ __forceinline__ float qswz(float x) {
    return __int_as_float(__builtin_amdgcn_ds_swizzle(__float_as_int(x), PAT));
}

__global__ void prep(const float* __restrict__ W_emb, const float* __restrict__ b_emb,
                     const float* __restrict__ W_ih,  const float* __restrict__ W_hh,
                     const float* __restrict__ b_ih,  const float* __restrict__ b_hh,
                     unsigned short* __restrict__ wsW)
{
    int tid = blockIdx.x * 256 + threadIdx.x;   // 0..36863
    if (tid >= 36864) return;
    int l    = tid & 63;
    int fid  = tid >> 6;          // 0..575
    int kt   = fid % 9;
    int cg16 = fid / 9;           // n-tile id 0..63  (== q4*16 + w)
    int l16  = l & 15, lg = l >> 4;
    int c    = l16 >> 2, q = l16 & 3;
    int col  = cg16 * 4 + c;      // h column
    int grow = q * 256 + col;     // gate row (i,f,g,o blocks of 256)
    union { unsigned short u16[8]; uint4 v; } pk;
    if (kt < 8) {
        int k0 = kt * 32 + lg * 8;
        const float* src = &W_hh[grow * 256 + k0];
        #pragma unroll
        for (int i = 0; i < 8; ++i) pk.u16[i] = f2bf(src[i]);
    } else {
        #pragma unroll
        for (int i = 0; i < 8; ++i) pk.u16[i] = 0;
        if (lg == 0) {
            float accf[6] = {0.f, 0.f, 0.f, 0.f, 0.f, 0.f};
            float accb = 0.f;
            for (int e = 0; e < 256; ++e) {
                float wv = W_ih[grow * 256 + e];
                accb += wv * b_emb[e];
                #pragma unroll
                for (int f = 0; f < 6; ++f) accf[f] += wv * W_emb[e * 6 + f];
            }
            #pragma unroll
            for (int f = 0; f < 6; ++f) pk.u16[f] = f2bf(accf[f]);
            pk.u16[6] = f2bf(accb + b_ih[grow] + b_hh[grow]);
        }
    }
    *reinterpret_cast<uint4*>(&wsW[(size_t)fid * 512 + l * 8]) = pk.v;
}

__device__ __forceinline__ float sigmoidf_(float x) { return 1.f / (1.f + __expf(-x)); }
__device__ __forceinline__ float tanhf_(float x) {
    float e = __expf(-2.f * fabsf(x));
    float r = (1.f - e) / (1.f + e);
    return copysignf(r, x);
}

__device__ __forceinline__ uint4 ld16_dev(const void* p) {   // fused load+wait
    uint4 v;
    asm volatile("global_load_dwordx4 %0, %1, off sc0 sc1\n\ts_waitcnt vmcnt(0)"
                 : "=v"(v) : "v"(p) : "memory");
    return v;
}
__device__ __forceinline__ void st4_dev(void* p, unsigned v) {
    asm volatile("global_store_dword %0, %1, off sc0 sc1" :: "v"(p), "v"(v) : "memory");
}

// quad-transpose gather: from acc (4 gate regs, quad rows) pick this lane's row
__device__ __forceinline__ void qgather(const f32x4& acc, bool qb0, bool qb1, float X[4]) {
    float g0, g1, g2, g3, x01, x23;
    g0 = qswz<0x8000>(acc[0]); g1 = qswz<0x8000>(acc[1]);
    g2 = qswz<0x8000>(acc[2]); g3 = qswz<0x8000>(acc[3]);
    x01 = qb0 ? g1 : g0; x23 = qb0 ? g3 : g2; X[0] = qb1 ? x23 : x01;
    g0 = qswz<0x8055>(acc[0]); g1 = qswz<0x8055>(acc[1]);
    g2 = qswz<0x8055>(acc[2]); g3 = qswz<0x8055>(acc[3]);
    x01 = qb0 ? g1 : g0; x23 = qb0 ? g3 : g2; X[1] = qb1 ? x23 : x01;
    g0 = qswz<0x80AA>(acc[0]); g1 = qswz<0x80AA>(acc[1]);
    g2 = qswz<0x80AA>(acc[2]); g3 = qswz<0x80AA>(acc[3]);
    x01 = qb0 ? g1 : g0; x23 = qb0 ? g3 : g2; X[2] = qb1 ? x23 : x01;
    g0 = qswz<0x80FF>(acc[0]); g1 = qswz<0x80FF>(acc[1]);
    g2 = qswz<0x80FF>(acc[2]); g3 = qswz<0x80FF>(acc[3]);
    x01 = qb0 ? g1 : g0; x23 = qb0 ? g3 : g2; X[3] = qb1 ? x23 : x01;
}

__global__ __launch_bounds__(1024, 4)
void lstm_main(const float* __restrict__ xin, const unsigned short* __restrict__ wsW,
               float* __restrict__ out, char* __restrict__ pub)
{
    // double-buffered by t parity: GEMM reads [p], EW writes [p^1] -> no BAR2
    __shared__ __align__(16) unsigned short hsh[2][32][264];  // 2x 16.9KB

    const int tid = threadIdx.x;
    const int w   = tid >> 6, l = tid & 63;
    const int l16 = l & 15,  lg = l >> 4;
    const int c   = l16 >> 2, q = l16 & 3;
    const bool qb0 = (q & 1), qb1 = (q & 2);
    const int bid = blockIdx.x;
    const int q4  = bid >> 6;            // column quarter 0..3
    const int g   = bid & 63;            // row group
    const int n0  = g * 32;
    const int j   = q4 * 64 + w * 4 + c; // lane's h column
    const int cg16 = q4 * 16 + w;

    // ---- persistent W: 9 frags = 36 VGPR, volatile-asm loads (no remat) ----
    frag_u Wf[9];
    #pragma unroll
    for (int kt = 0; kt < 9; ++kt) {
        const unsigned short* p = &wsW[(size_t)(cg16 * 9 + kt) * 512 + l * 8];
        asm volatile("global_load_dwordx4 %0, %1, off" : "=v"(Wf[kt].u4) : "v"(p));
    }
    asm volatile("s_waitcnt vmcnt(0)" ::: "memory");

    float cm0 = 0.f, cm1 = 0.f;   // cell state for my row (lg*4+q), m-tile 0/1

    // per-thread staged-unit geometry (constant across t)
    const int iuA = tid;                 // < 1026 always
    const int iuB = tid + 1024;          // valid only for tid<2
    const int pA_ord = iuA / PUB_UNITS, uA = iuA - pA_ord * PUB_UNITS;
    const int pB_ord = iuB / PUB_UNITS, uB = iuB - pB_ord * PUB_UNITS;
    const int pA = pA_ord + (pA_ord >= q4 ? 1 : 0);
    const int pB = pB_ord + (pB_ord >= q4 ? 1 : 0);

    for (int t = 0; t < TT; ++t) {
        const int want = t - 1;
        const int pw = want & 1;         // read-parity buffer (h(t-1))
        const int cw = t & 1;            // write-parity buffer (h(t))
        uint4 vA = make_uint4(0u, 0u, 0u, 0u);
        uint4 vB = make_uint4(0u, 0u, 0u, (unsigned)want);   // ok by default
        const char* srcA = nullptr; const char* srcB = nullptr;

        // ---- A. issue partner unit loads (no wait) ----
        if (t > 0) {
            const char* base = pub + (size_t)pw * 256 * PUB_STRIDE;
            srcA = base + (size_t)(g + 64 * pA) * PUB_STRIDE + uA * 16;
            asm volatile("global_load_dwordx4 %0, %1, off sc0 sc1"
                         : "=v"(vA) : "v"(srcA) : "memory");
            if (iuB < NUNITS3) {
                srcB = base + (size_t)(g + 64 * pB) * PUB_STRIDE + uB * 16;
                asm volatile("global_load_dwordx4 %0, %1, off sc0 sc1"
                             : "=v"(vB) : "v"(srcB) : "memory");
            }
        }

        // ---- B. x/bias A-frags (cached loads; overlap the in-flight sweep) ----
        frag_u xa0, xa1;
        xa0.u4 = (uint4){0u, 0u, 0u, 0u};
        xa1.u4 = (uint4){0u, 0u, 0u, 0u};
        if (lg == 0) {
            union { unsigned short u16[8]; uint4 v; } pk;
            const float* xp0 = xin + ((size_t)(n0 + l16) * TT + t) * 6;
            #pragma unroll
            for (int f = 0; f < 6; ++f) pk.u16[f] = f2bf(xp0[f]);
            pk.u16[6] = 0x3F80; pk.u16[7] = 0;
            xa0.u4 = pk.v;
            const float* xp1 = xin + ((size_t)(n0 + 16 + l16) * TT + t) * 6;
            #pragma unroll
            for (int f = 0; f < 6; ++f) pk.u16[f] = f2bf(xp1[f]);
            pk.u16[6] = 0x3F80; pk.u16[7] = 0;
            xa1.u4 = pk.v;
        }

        // ---- C. check tags once; retry only stale lanes with backoff ----
        if (t > 0) {
            asm volatile("s_waitcnt vmcnt(0)" ::: "memory");
            __builtin_amdgcn_sched_barrier(0);   // rule #18: no hoisting past wait
            bool okA = ((int)vA.w == want);
            bool okB = (iuB >= NUNITS3) || ((int)vB.w == want);
            int it = 0;
            while (__ballot(!(okA && okB)) != 0ull) {
                __builtin_amdgcn_s_sleep(1);
                if (!okA) { vA = ld16_dev(srcA); okA = ((int)vA.w == want); }
                if (!okB) { vB = ld16_dev(srcB); okB = ((int)vB.w == want); }
                if (++it > (1 << 13)) break;     // fail loud via absmax, not hang
            }
            // stage unit A (all threads) and unit B (tid<2)
            {
                const int D0 = 3 * uA;
                {   int r = D0 >> 5, d = D0 & 31;
                    *reinterpret_cast<unsigned*>(&hsh[pw][r][pA * 64 + 2 * d]) = vA.x; }
                if (D0 + 1 < 1024) { int r = (D0 + 1) >> 5, d = (D0 + 1) & 31;
                    *reinterpret_cast<unsigned*>(&hsh[pw][r][pA * 64 + 2 * d]) = vA.y; }
                if (D0 + 2 < 1024) { int r = (D0 + 2) >> 5, d = (D0 + 2) & 31;
                    *reinterpret_cast<unsigned*>(&hsh[pw][r][pA * 64 + 2 * d]) = vA.z; }
            }
            if (iuB < NUNITS3) {
                const int D0 = 3 * uB;
                {   int r = D0 >> 5, d = D0 & 31;
                    *reinterpret_cast<unsigned*>(&hsh[pw][r][pB * 64 + 2 * d]) = vB.x; }
                if (D0 + 1 < 1024) { int r = (D0 + 1) >> 5, d = (D0 + 1) & 31;
                    *reinterpret_cast<unsigned*>(&hsh[pw][r][pB * 64 + 2 * d]) = vB.y; }
                if (D0 + 2 < 1024) { int r = (D0 + 2) >> 5, d = (D0 + 2) & 31;
                    *reinterpret_cast<unsigned*>(&hsh[pw][r][pB * 64 + 2 * d]) = vB.z; }
            }
        }
        __syncthreads();   // BAR1: staged h(t-1) visible

        // ---- D. recurrent GEMM + x-tile (reads hsh[pw] only) ----
        f32x4 acc0 = (f32x4){0.f, 0.f, 0.f, 0.f};
        f32x4 acc1 = (f32x4){0.f, 0.f, 0.f, 0.f};
        if (t > 0) {
            #pragma unroll
            for (int kt = 0; kt < 8; ++kt) {
                s16x8 a0 = *reinterpret_cast<const s16x8*>(&hsh[pw][l16     ][kt * 32 + lg * 8]);
                s16x8 a1 = *reinterpret_cast<const s16x8*>(&hsh[pw][16 + l16][kt * 32 + lg * 8]);
                acc0 = __builtin_amdgcn_mfma_f32_16x16x32_bf16(a0, Wf[kt].s, acc0, 0, 0, 0);
                acc1 = __builtin_amdgcn_mfma_f32_16x16x32_bf16(a1, Wf[kt].s, acc1, 0, 0, 0);
            }
        }
        acc0 = __builtin_amdgcn_mfma_f32_16x16x32_bf16(xa0.s, Wf[8].s, acc0, 0, 0, 0);
        acc1 = __builtin_amdgcn_mfma_f32_16x16x32_bf16(xa1.s, Wf[8].s, acc1, 0, 0, 0);
        // (no BAR2: EW writes go to hsh[cw], disjoint from hsh[pw])

        // ---- E. quad-transpose gather + elementwise for OWN row q only ----
        float hn0, hn1;
        {
            float X[4];
            qgather(acc0, qb0, qb1, X);
            float cn = fmaf(sigmoidf_(X[1]), cm0, sigmoidf_(X[0]) * tanhf_(X[2]));
            cm0 = cn;
            hn0 = sigmoidf_(X[3]) * tanhf_(cn);
            qgather(acc1, qb0, qb1, X);
            cn = fmaf(sigmoidf_(X[1]), cm1, sigmoidf_(X[0]) * tanhf_(X[2]));
            cm1 = cn;
            hn1 = sigmoidf_(X[3]) * tanhf_(cn);
        }
        // write own h(t) into LDS buf cw (lane: row lg*4+q of each m-tile, col j)
        hsh[cw][lg * 4 + q     ][j] = f2bf(hn0);
        hsh[cw][16 + lg * 4 + q][j] = f2bf(hn1);
        __syncthreads();   // BAR3: own-quarter h(t) complete in LDS

        // ---- F. publish: 3 data dwords -> drain(DATA ONLY) -> tag -> out ----
        char* dst = nullptr;
        if (t < TT - 1 && tid < PUB_UNITS) {
            const int u = tid, D0 = 3 * u;
            unsigned px, py = 0, pz = 0;
            { int r = D0 >> 5, d = D0 & 31;
              px = *reinterpret_cast<const unsigned*>(&hsh[cw][r][q4 * 64 + 2 * d]); }
            if (D0 + 1 < 1024) { int r = (D0 + 1) >> 5, d = (D0 + 1) & 31;
              py = *reinterpret_cast<const unsigned*>(&hsh[cw][r][q4 * 64 + 2 * d]); }
            if (D0 + 2 < 1024) { int r = (D0 + 2) >> 5, d = (D0 + 2) & 31;
              pz = *reinterpret_cast<const unsigned*>(&hsh[cw][r][q4 * 64 + 2 * d]); }
            dst = pub + ((size_t)cw * 256 + bid) * PUB_STRIDE + u * 16;
            st4_dev(dst,     px);
            st4_dev(dst + 4, py);
            st4_dev(dst + 8, pz);
        }
        asm volatile("s_waitcnt vmcnt(0)" ::: "memory");  // data at MALL before tag
        if (t < TT - 1 && tid < PUB_UNITS)
            st4_dev(dst + 12, (unsigned)t);

        // out stores AFTER the tag: off the partners' critical path
        {
            int r = tid >> 5, d = tid & 31;
            unsigned hv = *reinterpret_cast<const unsigned*>(&hsh[cw][r][q4 * 64 + 2 * d]);
            float2 ov = make_float2(bf2f(hv & 0xffffu), bf2f(hv >> 16));
            *reinterpret_cast<float2*>(
                &out[((size_t)(n0 + r) * TT + t) * NH + q4 * 64 + 2 * d]) = ov;
        }
        // no barrier: next staging writes hsh[cw] PARTNER cols (disjoint from the
        // own-col reads above); GEMM(t+1) reads are fenced by BAR1(t+1).
    }
}

extern "C" void kernel_launch(void* const* d_in, const int* in_sizes, int n_in,
                              void* d_out, int out_size, void* d_ws, size_t ws_size,
                              hipStream_t stream)
{
    const float* xin   = (const float*)d_in[0];
    const float* W_emb = (const float*)d_in[1];
    const float* b_emb = (const float*)d_in[2];
    const float* W_ih  = (const float*)d_in[3];
    const float* W_hh  = (const float*)d_in[4];
    const float* b_ih  = (const float*)d_in[5];
    const float* b_hh  = (const float*)d_in[6];
    float* out = (float*)d_out;

    unsigned short* wsW = (unsigned short*)d_ws;
    char* pub = (char*)d_ws + OFF_PUB;

    (void)hipMemsetAsync(pub, 0xFF, PUB_BYTES, stream);  // tags -> -1 (never valid)
    prep<<<144, 256, 0, stream>>>(W_emb, b_emb, W_ih, W_hh, b_ih, b_hh, wsW);
    lstm_main<<<256, 1024, 0, stream>>>(xin, wsW, out, pub);
}